// Round 2
// baseline (4392.446 us; speedup 1.0000x reference)
//
#include <hip/hip_runtime.h>

#define NPTS   40000
#define NG     4
#define NK     64
#define ND     400
#define PT     256          // points per assign tile
#define NCHUNK 25           // ND / 16 (one 16x16x16 K-step per chunk)
#define NTILES 157          // ceil(NPTS / PT)
#define NBLK   64           // gather blocks per group (1 per CU, 256 total)
#define PPB    625          // points per gather block (64*625 = 40000)

typedef _Float16 f16x4 __attribute__((ext_vector_type(4)));
typedef float    f32x4 __attribute__((ext_vector_type(4)));

// ---------------------------------------------------------------------------
// Kernel A: scores GEMM on the MATRIX pipe via 2-way f16 split (x64 scaling),
// then argmax -> label only (rank/count machinery deleted — the linear
// gather no longer needs a sorted order).
//   p*64 = p1 + p2 (+eps<=2^-22), c*64 = c1 + c2; keep p1c1+p1c2+p2c1.
// MFMA v_mfma_f32_16x16x16_f16 (classic layout: A row=l%16,k=4*(l/16)+i;
// D row=4*(l/16)+reg, col=l%16). LDS rows padded to 20 f16: pair stride 5
// coprime with 16 -> conflict-free b64 reads/writes.
// ---------------------------------------------------------------------------
__global__ __launch_bounds__(256)
void assign_kernel(const float* __restrict__ patches,   // [NPTS][NG][ND]
                   const float* __restrict__ cent,      // [NG][NK][ND]
                   int*   __restrict__ lab)             // [NG][NPTS]
{
    const int g    = blockIdx.y;
    const int tile = blockIdx.x;
    const int t    = threadIdx.x;
    const int n0   = tile * PT;

    __shared__ _Float16 A1[PT][20];   // hi split of points, k-chunk resident
    __shared__ _Float16 A2[PT][20];   // lo split
    __shared__ _Float16 B1[NK][20];   // hi split of centroids
    __shared__ _Float16 B2[NK][20];   // lo split
    __shared__ float c2p[NK][4];
    __shared__ float c2s[NK];         // 0.5*||c||^2 * 4096 (matches scaled GEMM)

    {   // half squared norms (fp32, exact), scaled by 4096
        int k = t >> 2, j = t & 3;
        const float* c = cent + ((size_t)g * NK + k) * ND + 100 * j;
        float s = 0.0f;
        #pragma unroll
        for (int d = 0; d < 100; d += 4) {
            float4 v = *(const float4*)(c + d);
            s = fmaf(v.x, v.x, fmaf(v.y, v.y, fmaf(v.z, v.z, fmaf(v.w, v.w, s))));
        }
        c2p[k][j] = s;
    }
    __syncthreads();
    if (t < NK) c2s[t] = 2048.0f * (c2p[t][0] + c2p[t][1] + c2p[t][2] + c2p[t][3]);

    const int w   = t >> 6;      // wave 0..3 -> points [64w, 64w+64)
    const int l   = t & 63;
    const int q   = l >> 4;      // k-quad within MFMA operand
    const int r15 = l & 15;

    // fixed per-thread staging sources
    int nn = n0 + t; if (nn >= NPTS) nn = NPTS - 1;
    const float* prow = patches + ((size_t)nn * NG + g) * ND;
    const float* crow = cent + ((size_t)g * NK + (t >> 2)) * ND + 4 * (t & 3);

    f32x4 acc[4][4];   // 4 point-tiles x 4 cluster-tiles of 16x16 (64 VGPR)
    {
        f32x4 z = {0.f, 0.f, 0.f, 0.f};
        #pragma unroll
        for (int i = 0; i < 4; ++i)
            #pragma unroll
            for (int j = 0; j < 4; ++j) acc[i][j] = z;
    }

    float4 pp[4]; float4 pc;
    #pragma unroll
    for (int j = 0; j < 4; ++j) pp[j] = *(const float4*)(prow + 4 * j);
    pc = *(const float4*)(crow);

    for (int c = 0; c < NCHUNK; ++c) {
        // ---- stage + split-convert current chunk (x64 scale) ----
        #pragma unroll
        for (int j = 0; j < 4; ++j) {
            float4 v = pp[j];
            float s0 = v.x * 64.0f, s1 = v.y * 64.0f, s2 = v.z * 64.0f, s3 = v.w * 64.0f;
            _Float16 a0 = (_Float16)s0, a1 = (_Float16)s1, a2 = (_Float16)s2, a3 = (_Float16)s3;
            f16x4 h1 = {a0, a1, a2, a3};
            f16x4 h2 = {(_Float16)(s0 - (float)a0), (_Float16)(s1 - (float)a1),
                        (_Float16)(s2 - (float)a2), (_Float16)(s3 - (float)a3)};
            *(f16x4*)&A1[t][4 * j] = h1;
            *(f16x4*)&A2[t][4 * j] = h2;
        }
        {
            float4 v = pc;
            float s0 = v.x * 64.0f, s1 = v.y * 64.0f, s2 = v.z * 64.0f, s3 = v.w * 64.0f;
            _Float16 a0 = (_Float16)s0, a1 = (_Float16)s1, a2 = (_Float16)s2, a3 = (_Float16)s3;
            f16x4 h1 = {a0, a1, a2, a3};
            f16x4 h2 = {(_Float16)(s0 - (float)a0), (_Float16)(s1 - (float)a1),
                        (_Float16)(s2 - (float)a2), (_Float16)(s3 - (float)a3)};
            int cc = t >> 2, jj = t & 3;
            *(f16x4*)&B1[cc][4 * jj] = h1;
            *(f16x4*)&B2[cc][4 * jj] = h2;
        }
        __syncthreads();

        // ---- prefetch next chunk while matrix pipe works ----
        if (c + 1 < NCHUNK) {
            const int d0 = (c + 1) * 16;
            #pragma unroll
            for (int j = 0; j < 4; ++j) pp[j] = *(const float4*)(prow + d0 + 4 * j);
            pc = *(const float4*)(crow + d0);
        }

        // ---- fragments + 3-product MFMA ----
        f16x4 a1v[4], a2v[4], b1v[4], b2v[4];
        #pragma unroll
        for (int pi = 0; pi < 4; ++pi) {
            int p = 64 * w + 16 * pi + r15;          // A row = lane%16
            a1v[pi] = *(const f16x4*)&A1[p][4 * q];  // k = 4*(lane/16)+i
            a2v[pi] = *(const f16x4*)&A2[p][4 * q];
        }
        #pragma unroll
        for (int cj = 0; cj < 4; ++cj) {
            int n = 16 * cj + r15;                   // B col = lane%16
            b1v[cj] = *(const f16x4*)&B1[n][4 * q];
            b2v[cj] = *(const f16x4*)&B2[n][4 * q];
        }
        #pragma unroll
        for (int pi = 0; pi < 4; ++pi)
            #pragma unroll
            for (int cj = 0; cj < 4; ++cj) {
                acc[pi][cj] = __builtin_amdgcn_mfma_f32_16x16x16f16(a2v[pi], b1v[cj], acc[pi][cj], 0, 0, 0);
                acc[pi][cj] = __builtin_amdgcn_mfma_f32_16x16x16f16(a1v[pi], b2v[cj], acc[pi][cj], 0, 0, 0);
                acc[pi][cj] = __builtin_amdgcn_mfma_f32_16x16x16f16(a1v[pi], b1v[cj], acc[pi][cj], 0, 0, 0);
            }
        __syncthreads();
    }

    // ---- argmax epilogue: per-lane over 4 cluster-tiles, then 16-lane
    //      shfl_xor reduce (D row 4q+r = point, D col = cluster%16).
    //      Ties pick the LOWEST cluster index (matches jnp.argmax). ----
    #pragma unroll
    for (int pi = 0; pi < 4; ++pi) {
        #pragma unroll
        for (int r = 0; r < 4; ++r) {
            float m  = acc[pi][0][r] - c2s[r15];
            int best = r15;
            #pragma unroll
            for (int cj = 1; cj < 4; ++cj) {
                int n = 16 * cj + r15;
                float s = acc[pi][cj][r] - c2s[n];
                if (s > m) { m = s; best = n; }
            }
            #pragma unroll
            for (int off = 1; off < 16; off <<= 1) {
                float om = __shfl_xor(m, off);
                int   ob = __shfl_xor(best, off);
                if (om > m || (om == m && ob < best)) { m = om; best = ob; }
            }
            if (r15 == 0) {
                int p  = 64 * w + 16 * pi + 4 * q + r;
                int np = n0 + p;
                if (np < NPTS) lab[(size_t)g * NPTS + np] = best;
            }
        }
    }
}

// ---------------------------------------------------------------------------
// Linear gather: block (b,g) streams points [625b, 625(b+1)) of group g in
// ORDER, accumulating rows into a full per-block LDS accumulator [64][404]
// via ds_add_f32. No sort, no scan, no scatter. Row pad +4 floats keeps
// concurrent different-label atomics on distinct banks.
// 10 point-slots x 100 d-quads = 1000 active lanes of 1024.
// ---------------------------------------------------------------------------
__global__ __launch_bounds__(1024)
void gather_lin(const float* __restrict__ patches,  // [NPTS][NG][ND]
                const int*   __restrict__ lab,      // [NG][NPTS]
                float* __restrict__ psum,           // [NG][NBLK][NK][ND]
                int*   __restrict__ pcnt2)          // [NG][NBLK][NK]
{
    const int b = blockIdx.x, g = blockIdx.y;
    const int t = threadIdx.x;

    __shared__ float acc[NK][ND + 4];   // 103.4 KB
    __shared__ int   cnt[NK];

    for (int i = t; i < NK * (ND + 4); i += 1024) ((float*)acc)[i] = 0.0f;
    if (t < NK) cnt[t] = 0;
    __syncthreads();

    const int slot = t / 100;            // 0..9 active (t<1000)
    const int q    = t - slot * 100;     // d-quad 0..99

    if (t < 1000) {
        const int* lg = lab + (size_t)g * NPTS;
        const int start = b * PPB, end = start + PPB;
        #pragma unroll 2
        for (int n = start + slot; n < end; n += 10) {
            int L = lg[n];               // broadcast within slot
            float4 v = *(const float4*)(patches + ((size_t)n * NG + g) * ND + 4 * q);
            atomicAdd(&acc[L][4 * q + 0], v.x);
            atomicAdd(&acc[L][4 * q + 1], v.y);
            atomicAdd(&acc[L][4 * q + 2], v.z);
            atomicAdd(&acc[L][4 * q + 3], v.w);
            if (q == 0) atomicAdd(&cnt[L], 1);
        }
    }
    __syncthreads();

    float* dst = psum + ((size_t)(g * NBLK + b) * NK) * ND;
    for (int i = t; i < NK * 100; i += 1024) {
        int k = i / 100, qq = i - 100 * k;
        *(float4*)(dst + (size_t)k * ND + 4 * qq) = *(const float4*)&acc[k][4 * qq];
    }
    if (t < NK) pcnt2[((size_t)g * NBLK + b) * NK + t] = cnt[t];
}

// ---------------------------------------------------------------------------
// Update: block (g,k). Reduce NBLK partial sums + counts (all 4 groups for
// the empty-in-any-group rule), divide, write.
// ---------------------------------------------------------------------------
__global__ __launch_bounds__(128)
void update_kernel(const float* __restrict__ psum,     // [NG][NBLK][NK][ND]
                   const int*   __restrict__ pcnt2,    // [NG][NBLK][NK]
                   float* __restrict__ outc)           // [NG][NK][ND]
{
    const int gk = blockIdx.x;
    const int g = gk >> 6, k = gk & 63;
    const int t = threadIdx.x;

    __shared__ int cpart[NG][32];
    __shared__ int ctot[NG];

    {   // counts: 128 threads cover (group, block-pair)
        int gp = t >> 5, bb = t & 31;
        int s = pcnt2[((size_t)gp * NBLK + bb) * NK + k]
              + pcnt2[((size_t)gp * NBLK + bb + 32) * NK + k];
        cpart[gp][bb] = s;
    }
    __syncthreads();
    if (t < NG) {
        int s = 0;
        #pragma unroll
        for (int i = 0; i < 32; ++i) s += cpart[t][i];
        ctot[t] = s;
    }
    __syncthreads();

    const bool bad = (ctot[0] == 0) | (ctot[1] == 0) | (ctot[2] == 0) | (ctot[3] == 0);
    const int  c   = ctot[g];
    const float inv = 1.0f / (float)(c == 0 ? 1 : c);

    if (t < 100) {
        float4 s = make_float4(0.f, 0.f, 0.f, 0.f);
        const float* p = psum + (((size_t)g * NBLK) * NK + k) * ND + 4 * t;
        #pragma unroll 8
        for (int b = 0; b < NBLK; ++b) {
            float4 v = *(const float4*)(p + (size_t)b * NK * ND);
            s.x += v.x; s.y += v.y; s.z += v.z; s.w += v.w;
        }
        float4 o;
        o.x = bad ? 0.0f : s.x * inv;
        o.y = bad ? 0.0f : s.y * inv;
        o.z = bad ? 0.0f : s.z * inv;
        o.w = bad ? 0.0f : s.w * inv;
        *(float4*)(outc + (size_t)(g * NK + k) * ND + 4 * t) = o;
    }
}

extern "C" void kernel_launch(void* const* d_in, const int* in_sizes, int n_in,
                              void* d_out, int out_size, void* d_ws, size_t ws_size,
                              hipStream_t stream)
{
    const float* patches = (const float*)d_in[0];
    const float* cinit   = (const float*)d_in[1];
    float* out = (float*)d_out;

    const size_t CSZ = (size_t)NG * NK * ND;              // 102400
    float* centA = (float*)d_ws;
    float* centB = centA + CSZ;
    int*   lab   = (int*)(centB + CSZ);                   // NG*NPTS
    int*   pcnt2 = lab + (size_t)NG * NPTS;               // NG*NBLK*NK
    float* psum  = (float*)(pcnt2 + (size_t)NG * NBLK * NK); // NG*NBLK*NK*ND (26.2 MB)

    const float* cur = cinit;
    for (int e = 0; e < 10; ++e) {
        assign_kernel<<<dim3(NTILES, NG), 256, 0, stream>>>(patches, cur, lab);
        gather_lin<<<dim3(NBLK, NG), 1024, 0, stream>>>(patches, lab, psum, pcnt2);
        float* nxt = (e == 9) ? out : ((e & 1) ? centB : centA);
        update_kernel<<<dim3(NG * NK), 128, 0, stream>>>(psum, pcnt2, nxt);
        cur = nxt;
    }
}

// Round 3
// 1722.951 us; speedup vs baseline: 2.5494x; 2.5494x over previous
//
#include <hip/hip_runtime.h>

#define NPTS   40000
#define NG     4
#define NK     64
#define ND     400
#define PT     128          // points per assign tile (128 -> 1252 blocks, ~2% tail)
#define NCHUNK 25           // ND / 16 (one 16x16x16 K-step per chunk)
#define NTILES 313          // ceil(NPTS / PT)
#define NSPL   16           // gather splits per cluster

typedef _Float16 f16x4 __attribute__((ext_vector_type(4)));
typedef float    f32x4 __attribute__((ext_vector_type(4)));

// ---------------------------------------------------------------------------
// Kernel A: scores GEMM on the MATRIX pipe via 2-way f16 split (x64 scaling),
// argmax -> packed (rank<<8)|label + per-tile counts. Math identical to the
// verified round-1 kernel; only the tile height changed (256->128) to kill
// the 22% scheduling tail (628 blocks / 256 CUs -> 1252 blocks).
// Thread t stages row (t&127), dim-half (t>>7) of each 16-dim chunk.
// ---------------------------------------------------------------------------
__global__ __launch_bounds__(256)
void assign_kernel(const float* __restrict__ patches,   // [NPTS][NG][ND]
                   const float* __restrict__ cent,      // [NG][NK][ND]
                   int*   __restrict__ lr,              // [NG][NPTS] packed
                   int*   __restrict__ pcnt)            // [NG][NTILES][NK]
{
    const int g    = blockIdx.y;
    const int tile = blockIdx.x;
    const int t    = threadIdx.x;
    const int n0   = tile * PT;

    __shared__ _Float16 A1[PT][20];   // hi split of points, k-chunk resident
    __shared__ _Float16 A2[PT][20];   // lo split
    __shared__ _Float16 B1[NK][20];   // hi split of centroids
    __shared__ _Float16 B2[NK][20];   // lo split
    __shared__ float c2p[NK][4];
    __shared__ float c2s[NK];         // 0.5*||c||^2 * 4096 (matches scaled GEMM)
    __shared__ int   cnt[NK];

    if (t < NK) cnt[t] = 0;

    {   // half squared norms (fp32, exact), scaled by 4096
        int k = t >> 2, j = t & 3;
        const float* c = cent + ((size_t)g * NK + k) * ND + 100 * j;
        float s = 0.0f;
        #pragma unroll
        for (int d = 0; d < 100; d += 4) {
            float4 v = *(const float4*)(c + d);
            s = fmaf(v.x, v.x, fmaf(v.y, v.y, fmaf(v.z, v.z, fmaf(v.w, v.w, s))));
        }
        c2p[k][j] = s;
    }
    __syncthreads();
    if (t < NK) c2s[t] = 2048.0f * (c2p[t][0] + c2p[t][1] + c2p[t][2] + c2p[t][3]);

    const int w   = t >> 6;      // wave 0..3 -> point rows [32w, 32w+32)
    const int l   = t & 63;
    const int q   = l >> 4;      // k-quad within MFMA operand
    const int r15 = l & 15;

    // staging sources: thread t owns row (t&127), dim-half (t>>7)
    const int rh = t & 127;
    const int hh = t >> 7;
    int nn = n0 + rh; if (nn >= NPTS) nn = NPTS - 1;
    const float* prow = patches + ((size_t)nn * NG + g) * ND + 8 * hh;
    const float* crow = cent + ((size_t)g * NK + (t >> 2)) * ND + 4 * (t & 3);

    f32x4 acc[2][4];   // 2 point-tiles x 4 cluster-tiles of 16x16 (32 VGPR)
    {
        f32x4 z = {0.f, 0.f, 0.f, 0.f};
        #pragma unroll
        for (int i = 0; i < 2; ++i)
            #pragma unroll
            for (int j = 0; j < 4; ++j) acc[i][j] = z;
    }

    float4 pp[2]; float4 pc;
    pp[0] = *(const float4*)(prow);
    pp[1] = *(const float4*)(prow + 4);
    pc = *(const float4*)(crow);

    for (int c = 0; c < NCHUNK; ++c) {
        // ---- stage + split-convert current chunk (x64 scale) ----
        #pragma unroll
        for (int j2 = 0; j2 < 2; ++j2) {
            float4 v = pp[j2];
            float s0 = v.x * 64.0f, s1 = v.y * 64.0f, s2 = v.z * 64.0f, s3 = v.w * 64.0f;
            _Float16 a0 = (_Float16)s0, a1 = (_Float16)s1, a2 = (_Float16)s2, a3 = (_Float16)s3;
            f16x4 h1 = {a0, a1, a2, a3};
            f16x4 h2 = {(_Float16)(s0 - (float)a0), (_Float16)(s1 - (float)a1),
                        (_Float16)(s2 - (float)a2), (_Float16)(s3 - (float)a3)};
            *(f16x4*)&A1[rh][8 * hh + 4 * j2] = h1;
            *(f16x4*)&A2[rh][8 * hh + 4 * j2] = h2;
        }
        {
            float4 v = pc;
            float s0 = v.x * 64.0f, s1 = v.y * 64.0f, s2 = v.z * 64.0f, s3 = v.w * 64.0f;
            _Float16 a0 = (_Float16)s0, a1 = (_Float16)s1, a2 = (_Float16)s2, a3 = (_Float16)s3;
            f16x4 h1 = {a0, a1, a2, a3};
            f16x4 h2 = {(_Float16)(s0 - (float)a0), (_Float16)(s1 - (float)a1),
                        (_Float16)(s2 - (float)a2), (_Float16)(s3 - (float)a3)};
            int cc = t >> 2, jj = t & 3;
            *(f16x4*)&B1[cc][4 * jj] = h1;
            *(f16x4*)&B2[cc][4 * jj] = h2;
        }
        __syncthreads();

        // ---- prefetch next chunk while matrix pipe works ----
        if (c + 1 < NCHUNK) {
            const int d0 = (c + 1) * 16;
            pp[0] = *(const float4*)(prow + d0);
            pp[1] = *(const float4*)(prow + d0 + 4);
            pc = *(const float4*)(crow + d0);
        }

        // ---- fragments + 3-product MFMA ----
        f16x4 a1v[2], a2v[2], b1v[4], b2v[4];
        #pragma unroll
        for (int pi = 0; pi < 2; ++pi) {
            int p = 32 * w + 16 * pi + r15;          // A row = lane%16
            a1v[pi] = *(const f16x4*)&A1[p][4 * q];  // k = 4*(lane/16)+i
            a2v[pi] = *(const f16x4*)&A2[p][4 * q];
        }
        #pragma unroll
        for (int cj = 0; cj < 4; ++cj) {
            int n = 16 * cj + r15;                   // B col = lane%16
            b1v[cj] = *(const f16x4*)&B1[n][4 * q];
            b2v[cj] = *(const f16x4*)&B2[n][4 * q];
        }
        #pragma unroll
        for (int pi = 0; pi < 2; ++pi)
            #pragma unroll
            for (int cj = 0; cj < 4; ++cj) {
                acc[pi][cj] = __builtin_amdgcn_mfma_f32_16x16x16f16(a2v[pi], b1v[cj], acc[pi][cj], 0, 0, 0);
                acc[pi][cj] = __builtin_amdgcn_mfma_f32_16x16x16f16(a1v[pi], b2v[cj], acc[pi][cj], 0, 0, 0);
                acc[pi][cj] = __builtin_amdgcn_mfma_f32_16x16x16f16(a1v[pi], b1v[cj], acc[pi][cj], 0, 0, 0);
            }
        __syncthreads();
    }

    // ---- argmax epilogue: per-lane over 4 cluster-tiles, then 16-lane
    //      shfl_xor reduce (D row 4q+r = point, D col = cluster%16).
    //      Ties pick the LOWEST cluster index (matches jnp.argmax). ----
    #pragma unroll
    for (int pi = 0; pi < 2; ++pi) {
        #pragma unroll
        for (int r = 0; r < 4; ++r) {
            float m  = acc[pi][0][r] - c2s[r15];
            int best = r15;
            #pragma unroll
            for (int cj = 1; cj < 4; ++cj) {
                int n = 16 * cj + r15;
                float s = acc[pi][cj][r] - c2s[n];
                if (s > m) { m = s; best = n; }
            }
            #pragma unroll
            for (int off = 1; off < 16; off <<= 1) {
                float om = __shfl_xor(m, off);
                int   ob = __shfl_xor(best, off);
                if (om > m || (om == m && ob < best)) { m = om; best = ob; }
            }
            if (r15 == 0) {
                int p  = 32 * w + 16 * pi + 4 * q + r;
                int np = n0 + p;
                if (np < NPTS) {
                    int rk = atomicAdd(&cnt[best], 1);   // within-tile rank (int atomic)
                    lr[(size_t)g * NPTS + np] = (rk << 8) | best;
                }
            }
        }
    }
    __syncthreads();
    if (t < NK) pcnt[((size_t)g * NTILES + tile) * NK + t] = cnt[t];
}

// ---------------------------------------------------------------------------
// Fused scan+scatter: each block stages pcnt[g] (u16, 40 KB), computes
// cluster totals, cbase (prefix over k), and its own tile-prefix, then
// scatters. Replaces the 4-block serial scan_kernel + its launch.
// Tile 0 additionally publishes cbase/counts for gather/update.
// ---------------------------------------------------------------------------
__global__ __launch_bounds__(256)
void scatter2_kernel(const int* __restrict__ lr,     // [NG][NPTS]
                     const int* __restrict__ pcnt,   // [NG][NTILES][NK]
                     int* __restrict__ order,        // [NG][NPTS]
                     int* __restrict__ cbase,        // [NG][NK]
                     int* __restrict__ counts)       // [NG][NK]
{
    const int tile = blockIdx.x, g = blockIdx.y, t = threadIdx.x;
    __shared__ unsigned short cnt_tk[NTILES * NK];   // 40064 B (counts <= 128)
    __shared__ int part [4][NK];
    __shared__ int part2[4][NK];
    __shared__ int kbase[NK];
    __shared__ int tpre[NK];

    const int* pg = pcnt + (size_t)g * NTILES * NK;
    for (int i = t; i < NTILES * NK; i += 256)
        cnt_tk[i] = (unsigned short)pg[i];
    __syncthreads();

    {   // 4-way split sums: totals and own-tile prefix per k
        int k = t & 63, p = t >> 6;
        int s1 = 0, s2 = 0;
        for (int tl = p; tl < NTILES; tl += 4) {
            int v = cnt_tk[tl * NK + k];
            s1 += v;
            if (tl < tile) s2 += v;
        }
        part [p][k] = s1;
        part2[p][k] = s2;
    }
    __syncthreads();
    if (t < NK) {
        part[0][t] = part[0][t] + part[1][t] + part[2][t] + part[3][t];   // totals
        tpre[t]    = part2[0][t] + part2[1][t] + part2[2][t] + part2[3][t];
    }
    __syncthreads();
    if (t == 0) {
        int run = 0;
        for (int k = 0; k < NK; ++k) { kbase[k] = run; run += part[0][k]; }
    }
    __syncthreads();
    if (tile == 0 && t < NK) {
        cbase[g * NK + t]  = kbase[t];
        counts[g * NK + t] = part[0][t];
    }
    const int n = tile * PT + t;
    if (t < PT && n < NPTS) {
        int packed = lr[(size_t)g * NPTS + n];
        int L = packed & 63, r = packed >> 8;
        order[(size_t)g * NPTS + kbase[L] + tpre[L] + r] = n;
    }
}

// ---------------------------------------------------------------------------
// Gather: block = (split, k, g). 5 points x 100 lanes per iter, register acc,
// whole contiguous 1600B rows -> streaming-friendly, no hot-loop atomics.
// (round-1 proven version, unchanged)
// ---------------------------------------------------------------------------
__global__ __launch_bounds__(512, 2)
void gather_kernel(const float* __restrict__ patches,  // [NPTS][NG][ND]
                   const int*   __restrict__ order,    // [NG][NPTS]
                   const int*   __restrict__ cbase,    // [NG][NK]
                   const int*   __restrict__ counts,   // [NG][NK]
                   float* __restrict__ psum)           // [NG][NK][NSPL][ND]
{
    const int s = blockIdx.x, k = blockIdx.y, g = blockIdx.z;
    const int t = threadIdx.x;
    const int base = cbase[g * NK + k];
    const int cnt  = counts[g * NK + k];
    const int start = base + (cnt * s) / NSPL;
    const int end   = base + (cnt * (s + 1)) / NSPL;

    const int slot = t / 100;          // 0..4 active (t<500)
    const int q    = t - slot * 100;   // d-quad 0..99

    float4 acc = make_float4(0.f, 0.f, 0.f, 0.f);
    if (t < 500) {
        const int* ord = order + (size_t)g * NPTS;
        #pragma unroll 4
        for (int i = start + slot; i < end; i += 5) {
            int n = ord[i];
            float4 v = *(const float4*)(patches + ((size_t)n * NG + g) * ND + 4 * q);
            acc.x += v.x; acc.y += v.y; acc.z += v.z; acc.w += v.w;
        }
    }

    __shared__ float sums[ND];
    for (int i = t; i < ND; i += 512) sums[i] = 0.0f;
    __syncthreads();
    if (t < 500) {
        atomicAdd(&sums[4 * q + 0], acc.x);
        atomicAdd(&sums[4 * q + 1], acc.y);
        atomicAdd(&sums[4 * q + 2], acc.z);
        atomicAdd(&sums[4 * q + 3], acc.w);
    }
    __syncthreads();
    if (t < 100) {
        float* dst = psum + (((size_t)(g * NK + k)) * NSPL + s) * ND + 4 * t;
        *(float4*)dst = *(const float4*)&sums[4 * t];
    }
}

// ---------------------------------------------------------------------------
// Update: reduce NSPL partials, divide (1 if empty), zero clusters empty in
// ANY group. (round-1 proven version, unchanged)
// ---------------------------------------------------------------------------
__global__ __launch_bounds__(128)
void update_kernel(const float* __restrict__ psum,     // [NG][NK][NSPL][ND]
                   const int*   __restrict__ counts,   // [NG][NK]
                   float* __restrict__ outc)           // [NG][NK][ND]
{
    const int gk = blockIdx.x;
    const int g = gk >> 6, k = gk & 63;
    const int t = threadIdx.x;

    const bool bad = (counts[0 * NK + k] == 0) | (counts[1 * NK + k] == 0) |
                     (counts[2 * NK + k] == 0) | (counts[3 * NK + k] == 0);
    const int  c  = counts[g * NK + k];
    const float inv = 1.0f / (float)(c == 0 ? 1 : c);

    if (t < 100) {
        float4 s = make_float4(0.f, 0.f, 0.f, 0.f);
        const float* p = psum + ((size_t)gk * NSPL) * ND + 4 * t;
        #pragma unroll
        for (int sp = 0; sp < NSPL; ++sp) {
            float4 v = *(const float4*)(p + (size_t)sp * ND);
            s.x += v.x; s.y += v.y; s.z += v.z; s.w += v.w;
        }
        float4 o;
        o.x = bad ? 0.0f : s.x * inv;
        o.y = bad ? 0.0f : s.y * inv;
        o.z = bad ? 0.0f : s.z * inv;
        o.w = bad ? 0.0f : s.w * inv;
        *(float4*)(outc + (size_t)gk * ND + 4 * t) = o;
    }
}

extern "C" void kernel_launch(void* const* d_in, const int* in_sizes, int n_in,
                              void* d_out, int out_size, void* d_ws, size_t ws_size,
                              hipStream_t stream)
{
    const float* patches = (const float*)d_in[0];
    const float* cinit   = (const float*)d_in[1];
    float* out = (float*)d_out;

    const size_t CSZ = (size_t)NG * NK * ND;              // 102400
    float* centA = (float*)d_ws;
    float* centB = centA + CSZ;
    int* lr       = (int*)(centB + CSZ);                  // NG*NPTS
    int* pcnt     = lr + (size_t)NG * NPTS;               // NG*NTILES*NK
    int* cbase    = pcnt + (size_t)NG * NTILES * NK;      // NG*NK
    int* counts   = cbase + NG * NK;                      // NG*NK
    int* order    = counts + NG * NK;                     // NG*NPTS
    float* psum   = (float*)(order + (size_t)NG * NPTS);  // NG*NK*NSPL*ND

    const float* cur = cinit;
    for (int e = 0; e < 10; ++e) {
        assign_kernel<<<dim3(NTILES, NG), 256, 0, stream>>>(patches, cur, lr, pcnt);
        scatter2_kernel<<<dim3(NTILES, NG), 256, 0, stream>>>(lr, pcnt, order, cbase, counts);
        gather_kernel<<<dim3(NSPL, NK, NG), 512, 0, stream>>>(patches, order, cbase, counts, psum);
        float* nxt = (e == 9) ? out : ((e & 1) ? centB : centA);
        update_kernel<<<dim3(NG * NK), 128, 0, stream>>>(psum, counts, nxt);
        cur = nxt;
    }
}